// Round 4
// baseline (243.941 us; speedup 1.0000x reference)
//
#include <hip/hip_runtime.h>
#include <hip/hip_bf16.h>
#include <math.h>

typedef unsigned short u16;
typedef unsigned int u32;
typedef __bf16 bf16;
typedef __bf16 bf16x8 __attribute__((ext_vector_type(8)));
typedef float f32x4 __attribute__((ext_vector_type(4)));
typedef float f32x16 __attribute__((ext_vector_type(16)));
typedef u16 u16x2 __attribute__((ext_vector_type(2)));
typedef u16 u16x4 __attribute__((ext_vector_type(4)));
typedef u16 u16x8 __attribute__((ext_vector_type(8)));
typedef u32 u32x4 __attribute__((ext_vector_type(4)));

// scale = 1/sqrt(64) * log2(e)  (folded into Q; softmax uses exp2)
#define QSCALE 0.1803368801111204f

// fp32 -> bf16 (RNE): native cast -> v_cvt_pk_bf16_f32 pairs on gfx950
static __device__ __forceinline__ u16 f2b(float f) {
  return __builtin_bit_cast(u16, (bf16)f);
}
static __device__ __forceinline__ float b2f(u16 u) {
  return __builtin_bit_cast(float, (u32)u << 16);
}
static __device__ __forceinline__ u32 pack2(float a, float b) {
  u16x2 p = { f2b(a), f2b(b) };   // low u16 = a (even k), high = b
  return __builtin_bit_cast(u32, p);
}

static __device__ __forceinline__ f32x4 mfma16(u16x8 a, u16x8 b, f32x4 c) {
  return __builtin_amdgcn_mfma_f32_16x16x32_bf16(
      __builtin_bit_cast(bf16x8, a), __builtin_bit_cast(bf16x8, b), c, 0, 0, 0);
}
static __device__ __forceinline__ f32x16 mfma32(u16x8 a, u16x8 b, f32x16 c) {
  return __builtin_amdgcn_mfma_f32_32x32x16_bf16(
      __builtin_bit_cast(bf16x8, a), __builtin_bit_cast(bf16x8, b), c, 0, 0, 0);
}

// swap a's upper 32 lanes with b's lower 32 lanes (v_permlane32_swap_b32)
static __device__ __forceinline__ void pl32swap(u32& a, u32& b) {
  asm("v_permlane32_swap_b32 %0, %1" : "+v"(a), "+v"(b));
}

// async global->LDS, 16B per lane; LDS ptr must be wave-uniform
static __device__ __forceinline__ void glds16(const u16* g, u16* l) {
  __builtin_amdgcn_global_load_lds(
      (const __attribute__((address_space(1))) void*)g,
      (__attribute__((address_space(3))) void*)l, 16, 0, 0);
}

#define WAIT_VM0() asm volatile("s_waitcnt vmcnt(0)" ::: "memory")

// Bank swizzle: rows are 64 u16 (128B) = 8 slots of 16B.
// slot ^= (row&7)^((row>>3)&7): distinct bank-quads both for in-order 8-lane
// groups (row bits 0-2) AND lane-quads {l,l+16,l+32,l+48} (row bit 4 / hh bit).
static __device__ __forceinline__ int swz(int row) {
  return (row & 7) ^ ((row >> 3) & 7);
}
static __device__ __forceinline__ u16x8 ldsrd(const u16* base, int row, int slot) {
  return *(const u16x8*)(base + row * 64 + ((slot ^ swz(row)) * 8));
}

// all casts (x + 4 weights) in one grid-stride launch, f32x4 granules
__global__ void cast_all(const float* __restrict__ x,
                         const float* __restrict__ Wq, const float* __restrict__ Wk,
                         const float* __restrict__ Wv, const float* __restrict__ Wo,
                         u16* __restrict__ x16, u16* __restrict__ wqkv,
                         u16* __restrict__ wo16) {
  int i = blockIdx.x * blockDim.x + threadIdx.x;
  int stride = gridDim.x * blockDim.x;
  for (; i < 1703936; i += stride) {
    const float* src; u16* dst; int j;
    if (i < 1048576)      { src = x;  dst = x16;            j = i; }
    else if (i < 1310720) { src = Wq; dst = wqkv;           j = i - 1048576; }
    else if (i < 1376256) { src = Wk; dst = wqkv + 1048576; j = i - 1310720; }
    else if (i < 1441792) { src = Wv; dst = wqkv + 1310720; j = i - 1376256; }
    else                  { src = Wo; dst = wo16;           j = i - 1441792; }
    f32x4 v = ((const f32x4*)src)[j];
    u16x4 o;
#pragma unroll
    for (int r = 0; r < 4; r++) o[r] = f2b(v[r]);
    ((u16x4*)dst)[j] = o;
  }
}

// V [kh][t][d] bf16 -> V^T [kh][d][t] bf16, 64x64 LDS tiles
__global__ void transpose_v(const u16* __restrict__ vb, u16* __restrict__ vt) {
  __shared__ u16 T[64][72];
  const int kh = blockIdx.y;
  const int t0 = blockIdx.x * 64;
  const int tid = threadIdx.x;
  const int r = tid >> 2, c0 = (tid & 3) * 16;
  const u16* src = vb + ((size_t)kh * 4096 + t0 + r) * 64 + c0;
  *(u16x8*)&T[r][c0] = *(const u16x8*)src;
  *(u16x8*)&T[r][c0 + 8] = *(const u16x8*)(src + 8);
  __syncthreads();
  const int d = tid >> 2, j0 = (tid & 3) * 16;
  u16x8 o0, o1;
#pragma unroll
  for (int j = 0; j < 8; j++) o0[j] = T[j0 + j][d];
#pragma unroll
  for (int j = 0; j < 8; j++) o1[j] = T[j0 + 8 + j][d];
  u16* dst = vt + ((size_t)kh * 64 + d) * 4096 + t0 + j0;
  *(u16x8*)dst = o0;
  *(u16x8*)(dst + 8) = o1;
}

// C = A @ B^T (+bias). A [M][K] bf16, B [N][K] bf16. 128x128 tile, BK=64, 256 thr.
// 2-phase pipeline: stage(t+1) issued before compute(t); one vmcnt(0)+barrier per step.
// Swapped MFMA: lane holds C^T[n=...+4g+reg][m=...+c] -> packed stores along n.
template<int MODE>
__global__ __launch_bounds__(256, 2) void gemm_bt(
    const u16* __restrict__ A, const u16* __restrict__ B,
    const float* __restrict__ b0, const float* __restrict__ b1,
    const float* __restrict__ b2,
    float* __restrict__ outF,
    u16* __restrict__ qs, u16* __restrict__ kb, u16* __restrict__ vb,
    int K) {
  __shared__ u16 As[2][128 * 64];
  __shared__ u16 Bs[2][128 * 64];
  const int t = threadIdx.x, w = t >> 6, l = t & 63;
  const int c = l & 15, g = l >> 4;
  const int n0 = blockIdx.x * 128, m0 = blockIdx.y * 128;
  const int nrow0 = (w >> 1) * 64, mrow0 = (w & 1) * 64;
  const int srow = l >> 3, sslot = l & 7;

  f32x4 acc[4][4];
  f32x4 z = {0.f, 0.f, 0.f, 0.f};
#pragma unroll
  for (int i = 0; i < 4; i++)
#pragma unroll
    for (int j = 0; j < 4; j++) acc[i][j] = z;

  // prologue: stage step 0 -> buf 0
#pragma unroll
  for (int p = 0; p < 4; p++) {
    int row = p * 32 + w * 8 + srow;
    int ss = sslot ^ swz(row);
    glds16(A + (size_t)(m0 + row) * K + ss * 8, &As[0][p * 2048 + w * 512]);
    glds16(B + (size_t)(n0 + row) * K + ss * 8, &Bs[0][p * 2048 + w * 512]);
  }
  WAIT_VM0();
  __builtin_amdgcn_s_barrier();

  const int NS = K >> 6;
  for (int st = 0; st < NS; ++st) {
    const int cur = st & 1;
    if (st + 1 < NS) {
      int kt = (st + 1) * 64;
#pragma unroll
      for (int p = 0; p < 4; p++) {
        int row = p * 32 + w * 8 + srow;
        int ss = sslot ^ swz(row);
        glds16(A + (size_t)(m0 + row) * K + kt + ss * 8, &As[cur ^ 1][p * 2048 + w * 512]);
        glds16(B + (size_t)(n0 + row) * K + kt + ss * 8, &Bs[cur ^ 1][p * 2048 + w * 512]);
      }
    }
    __builtin_amdgcn_s_setprio(1);
#pragma unroll
    for (int ks = 0; ks < 2; ks++) {
      u16x8 af[4], bf[4];
#pragma unroll
      for (int nj = 0; nj < 4; nj++) af[nj] = ldsrd(Bs[cur], nrow0 + 16 * nj + c, g + 4 * ks);
#pragma unroll
      for (int mi = 0; mi < 4; mi++) bf[mi] = ldsrd(As[cur], mrow0 + 16 * mi + c, g + 4 * ks);
#pragma unroll
      for (int nj = 0; nj < 4; nj++)
#pragma unroll
        for (int mi = 0; mi < 4; mi++) acc[nj][mi] = mfma16(af[nj], bf[mi], acc[nj][mi]);
    }
    __builtin_amdgcn_s_setprio(0);
    WAIT_VM0();
    __builtin_amdgcn_s_barrier();
  }

#pragma unroll
  for (int nj = 0; nj < 4; nj++) {
#pragma unroll
    for (int mi = 0; mi < 4; mi++) {
      int n = n0 + nrow0 + 16 * nj + 4 * g;   // 4 consecutive n (reg 0..3)
      int m = m0 + mrow0 + 16 * mi + c;
      f32x4 v = acc[nj][mi];
      if (MODE == 1) {
        f32x4 bb = *(const f32x4*)(b0 + n);
        v += bb;
        *(f32x4*)(outF + (size_t)m * 1024 + n) = v;
      } else {
        if (n < 1024) {              // Q -> scaled bf16
          f32x4 bb = *(const f32x4*)(b0 + n);
          v += bb;
          u16x4 q;
#pragma unroll
          for (int r = 0; r < 4; r++) q[r] = f2b(v[r] * QSCALE);
          *(u16x4*)(qs + (size_t)m * 1024 + n) = q;
        } else if (n < 1280) {       // K -> fp32 d_out + bf16 ws [kh][t][d]
          int nn = n - 1024, khh = nn >> 6, d = nn & 63;
          f32x4 bb = *(const f32x4*)(b1 + nn);
          v += bb;
          *(f32x4*)(outF + (size_t)4194304 + (size_t)(khh * 4096 + m) * 64 + d) = v;
          u16x4 kq;
#pragma unroll
          for (int r = 0; r < 4; r++) kq[r] = f2b(v[r]);
          *(u16x4*)(kb + (size_t)(khh * 4096 + m) * 64 + d) = kq;
        } else {                     // V -> fp32 d_out + bf16 ws [kh][t][d] (coalesced)
          int nn = n - 1280, khh = nn >> 6, d = nn & 63;
          f32x4 bb = *(const f32x4*)(b2 + nn);
          v += bb;
          *(f32x4*)(outF + (size_t)5242880 + (size_t)(khh * 4096 + m) * 64 + d) = v;
          u16x4 vq;
#pragma unroll
          for (int r = 0; r < 4; r++) vq[r] = f2b(v[r]);
          *(u16x4*)(vb + (size_t)(khh * 4096 + m) * 64 + d) = vq;
        }
      }
    }
  }
}

// Flash attention fwd, 32x32x16 MFMA, KV-split: grid (32 q-tiles, 16 heads, nz).
// 4 waves x 32 q-rows. Swapped QK^T -> S^T lane-local; P -> PV B-frag in registers
// via permlane32_swap; l via ones-MFMA. Stores UNNORMALIZED O (bf16) + (m,l).
__global__ __launch_bounds__(256, 4) void attn_fwd(
    const u16* __restrict__ qs, const u16* __restrict__ kb,
    const u16* __restrict__ vt, u16* __restrict__ op0, u16* __restrict__ op1,
    float* __restrict__ ml, int ntiles) {
  __shared__ u16 Ks[2][64 * 64];   // [key][d] swz
  __shared__ u16 Vs[2][64 * 64];   // [d][key] swz (V^T tile)
  const int h = blockIdx.y, kh = h >> 2, zz = blockIdx.z;
  const int q0 = blockIdx.x * 128;
  const int kv0 = zz * ntiles * 64;
  const int t = threadIdx.x, w = t >> 6, l = t & 63;
  const int ql = l & 31, hh = l >> 5;
  const int srow = l >> 3, sslot = l & 7;

  const u16* kbase = kb + (size_t)kh * 262144 + (size_t)kv0 * 64;
  const u16* vbase = vt + (size_t)kh * 262144 + kv0;

  // Q fragments (B-role): row q = q0+w*32+ql, d = 16ks + 8hh + j (scale pre-folded)
  u16x8 qf[4];
#pragma unroll
  for (int ks = 0; ks < 4; ks++)
    qf[ks] = *(const u16x8*)(qs + (size_t)(q0 + w * 32 + ql) * 1024 + h * 64 + ks * 16 + hh * 8);

  u16x8 onesf;
#pragma unroll
  for (int j = 0; j < 8; j++) onesf[j] = 0x3F80;  // bf16 1.0

  f32x16 o0v, o1v, lacc;
#pragma unroll
  for (int i = 0; i < 16; i++) { o0v[i] = 0.f; o1v[i] = 0.f; lacc[i] = 0.f; }
  float m_r = -INFINITY;

  // prologue: stage tile 0 -> buf 0
#pragma unroll
  for (int p = 0; p < 2; p++) {
    int row = p * 32 + w * 8 + srow;
    int ss = sslot ^ swz(row);
    glds16(kbase + (size_t)row * 64 + ss * 8, &Ks[0][p * 2048 + w * 512]);
    glds16(vbase + (size_t)row * 4096 + ss * 8, &Vs[0][p * 2048 + w * 512]);
  }
  WAIT_VM0();
  __builtin_amdgcn_s_barrier();

  for (int tt = 0; tt < ntiles; ++tt) {
    const int cur = tt & 1;
    const u16* KsC = Ks[cur];
    const u16* VsC = Vs[cur];
    if (tt + 1 < ntiles) {
      int kv = (tt + 1) * 64;
#pragma unroll
      for (int p = 0; p < 2; p++) {
        int row = p * 32 + w * 8 + srow;
        int ss = sslot ^ swz(row);
        glds16(kbase + (size_t)(kv + row) * 64 + ss * 8, &Ks[cur ^ 1][p * 2048 + w * 512]);
        glds16(vbase + (size_t)row * 4096 + kv + ss * 8, &Vs[cur ^ 1][p * 2048 + w * 512]);
      }
    }

    // S^T = mfma(K, Q): lane holds S[q=ql][k = 32kj + (reg&3)+8(reg>>2)+4hh]
    f32x16 sA, sB;
#pragma unroll
    for (int i = 0; i < 16; i++) { sA[i] = 0.f; sB[i] = 0.f; }
    __builtin_amdgcn_s_setprio(1);
#pragma unroll
    for (int ks = 0; ks < 4; ks++) {
      u16x8 kf0 = ldsrd(KsC, ql, 2 * ks + hh);
      u16x8 kf1 = ldsrd(KsC, 32 + ql, 2 * ks + hh);
      sA = mfma32(kf0, qf[ks], sA);
      sB = mfma32(kf1, qf[ks], sB);
    }
    __builtin_amdgcn_s_setprio(0);

    // row max (own 32 values, tree) + partner half via lane^32
    float mx[16];
#pragma unroll
    for (int i = 0; i < 16; i++) mx[i] = fmaxf(sA[i], sB[i]);
#pragma unroll
    for (int stp = 8; stp > 0; stp >>= 1)
#pragma unroll
      for (int i = 0; i < stp; i++) mx[i] = fmaxf(mx[i], mx[i + stp]);
    float pm = fmaxf(mx[0], __shfl_xor(mx[0], 32));

    if (!__all(pm - m_r <= 8.0f)) {       // defer-max (THR=8)
      float mn = fmaxf(m_r, pm);
      float fac = __builtin_amdgcn_exp2f(m_r - mn);  // first tile: 0
      m_r = mn;
      o0v *= fac; o1v *= fac; lacc *= fac;
    }

    // P = exp2(S - m), packed bf16 pairs (8 u32 words per 32-k block)
    u32 pw0[8], pw1[8];
#pragma unroll
    for (int i = 0; i < 8; i++) {
      pw0[i] = pack2(__builtin_amdgcn_exp2f(sA[2 * i] - m_r),
                     __builtin_amdgcn_exp2f(sA[2 * i + 1] - m_r));
      pw1[i] = pack2(__builtin_amdgcn_exp2f(sB[2 * i] - m_r),
                     __builtin_amdgcn_exp2f(sB[2 * i + 1] - m_r));
    }

    // PV + l: per 16-k step build B-frag from registers via permlane32_swap
    __builtin_amdgcn_s_setprio(1);
#pragma unroll
    for (int t4 = 0; t4 < 4; t4++) {
      u32 a0, a1, b0, b1;
      if (t4 == 0)      { a0 = pw0[0]; a1 = pw0[1]; b0 = pw0[2]; b1 = pw0[3]; }
      else if (t4 == 1) { a0 = pw0[4]; a1 = pw0[5]; b0 = pw0[6]; b1 = pw0[7]; }
      else if (t4 == 2) { a0 = pw1[0]; a1 = pw1[1]; b0 = pw1[2]; b1 = pw1[3]; }
      else              { a0 = pw1[4]; a1 = pw1[5]; b0 = pw1[6]; b1 = pw1[7]; }
      pl32swap(a0, b0);
      pl32swap(a1, b1);
      u32x4 pv4 = {a0, a1, b0, b1};
      u16x8 pf = __builtin_bit_cast(u16x8, pv4);
      u16x8 vf0 = ldsrd(VsC, ql, 2 * t4 + hh);
      u16x8 vf1 = ldsrd(VsC, 32 + ql, 2 * t4 + hh);
      o0v = mfma32(vf0, pf, o0v);
      o1v = mfma32(vf1, pf, o1v);
      lacc = mfma32(onesf, pf, lacc);
    }
    __builtin_amdgcn_s_setprio(0);

    WAIT_VM0();
    __builtin_amdgcn_s_barrier();
  }

  // epilogue: unnormalized O (bf16) + per-q (m, l)
  u16* dst = zz ? op1 : op0;
  const int q = q0 + w * 32 + ql;
  const size_t obase = (size_t)q * 1024 + h * 64;
#pragma unroll
  for (int dj = 0; dj < 2; dj++)
#pragma unroll
    for (int rq = 0; rq < 4; rq++) {
      u16x4 ov;
#pragma unroll
      for (int r = 0; r < 4; r++)
        ov[r] = f2b(dj ? o1v[rq * 4 + r] : o0v[rq * 4 + r]);
      *(u16x4*)(dst + obase + dj * 32 + rq * 8 + hh * 4) = ov;
    }
  if (hh == 0)
    *(float2*)(ml + (((size_t)zz * 16 + h) * 4096 + q) * 2) = make_float2(m_r, lacc[0]);
}

// combine KV-split partials (in place over op0 -> ATT bf16)
__global__ void merge_o(u16* __restrict__ op0, const u16* __restrict__ op1,
                        const float* __restrict__ ml, int nz) {
  int idx = blockIdx.x * blockDim.x + threadIdx.x;  // 512K threads, 8 elems each
  int q = idx >> 7, c8 = idx & 127;
  int h = c8 >> 3;
  size_t off = (size_t)q * 1024 + c8 * 8;
  u16x8 a = *(u16x8*)(op0 + off);
  const float2 ml0 = *(const float2*)(ml + ((size_t)h * 4096 + q) * 2);
  u16x8 r;
  if (nz == 2) {
    u16x8 b = *(const u16x8*)(op1 + off);
    const float2 ml1 = *(const float2*)(ml + ((size_t)(16 + h) * 4096 + q) * 2);
    float m = fmaxf(ml0.x, ml1.x);
    float e0 = exp2f(ml0.x - m), e1 = exp2f(ml1.x - m);
    float inv = 1.f / (ml0.y * e0 + ml1.y * e1);
    e0 *= inv; e1 *= inv;
#pragma unroll
    for (int j = 0; j < 8; j++) r[j] = f2b(b2f(a[j]) * e0 + b2f(b[j]) * e1);
  } else {
    float inv = 1.f / ml0.y;
#pragma unroll
    for (int j = 0; j < 8; j++) r[j] = f2b(b2f(a[j]) * inv);
  }
  *(u16x8*)(op0 + off) = r;
}

extern "C" void kernel_launch(void* const* d_in, const int* in_sizes, int n_in,
                              void* d_out, int out_size, void* d_ws, size_t ws_size,
                              hipStream_t stream) {
  const float* x  = (const float*)d_in[0];
  const float* Wq = (const float*)d_in[1];
  const float* bq = (const float*)d_in[2];
  const float* Wk = (const float*)d_in[3];
  const float* bk = (const float*)d_in[4];
  const float* Wv = (const float*)d_in[5];
  const float* bv = (const float*)d_in[6];
  const float* Wo = (const float*)d_in[7];
  const float* bo = (const float*)d_in[8];
  float* out = (float*)d_out;
  char* ws = (char*)d_ws;

  u16* X16  = (u16*)(ws);                // 8MB x bf16 [4096][1024]; later OP0/ATT
  u16* WQKV = (u16*)(ws + 8388608);      // 3MB [1536][1024]; dead after gemm<0>
  u16* VT   = (u16*)(ws + 8388608);      // 2MB V^T bf16 [4][64][4096] (aliases WQKV)
  float* ML = (float*)(ws + 10485760);   // 1MB (m,l) [nz][16][4096][2] f32
  u16* WO16 = (u16*)(ws + 11534336);     // 2MB [1024][1024]
  u16* QS   = (u16*)(ws + 13631488);     // 8MB scaled Q bf16 [4096][1024]
  u16* KB   = (u16*)(ws + 22020096);     // 2MB K bf16 [4][4096][64]
  u16* VB   = (u16*)(ws + 24117248);     // 2MB V bf16 [4][4096][64]
  u16* OP1  = (u16*)(ws + 26214400);     // 8MB partial O (z=1), only if ws allows
  u16* ATT  = X16;                       // x dead after QKV gemm; OP0 = ATT region

  const int nz = (ws_size >= (size_t)34603008) ? 2 : 1;

  cast_all<<<2048, 256, 0, stream>>>(x, Wq, Wk, Wv, Wo, X16, WQKV, WO16);

  gemm_bt<0><<<dim3(12, 32), 256, 0, stream>>>(X16, WQKV, bq, bk, bv, out, QS, KB, VB, 1024);
  transpose_v<<<dim3(64, 4), 256, 0, stream>>>(VB, VT);
  attn_fwd<<<dim3(32, 16, nz), 256, 0, stream>>>(QS, KB, VT, ATT, OP1, ML, 64 / nz);
  merge_o<<<2048, 256, 0, stream>>>(ATT, OP1, ML, nz);
  gemm_bt<1><<<dim3(8, 32), 256, 0, stream>>>(ATT, WO16, bo, nullptr, nullptr, out,
                                              nullptr, nullptr, nullptr, 1024);
}